// Round 1
// baseline (17239.366 us; speedup 1.0000x reference)
//
#include <hip/hip_runtime.h>
#include <math.h>

#define N_NODES 2000
#define N_EDGES 32000
#define H 300
#define HHALF 150
#define NLAYERS 30
#define NH (N_NODES * H)   // 600000
#define EH (N_EDGES * H)   // 9600000

// ---------------------------------------------------------------- utilities
__global__ __launch_bounds__(256) void zero_buf(float* __restrict__ p, int n) {
    int i = blockIdx.x * blockDim.x + threadIdx.x;
    if (i < n) p[i] = 0.f;
}

// ---------------------------------------------------------------- embeddings
__global__ __launch_bounds__(256) void node_embed(const float* __restrict__ x,
                                                  const float* __restrict__ W,
                                                  const float* __restrict__ b,
                                                  float* __restrict__ node) {
    int i = blockIdx.x * blockDim.x + threadIdx.x;
    if (i >= NH) return;
    int n = i / H, h = i % H;
    float acc = b[h];
#pragma unroll
    for (int k = 0; k < 4; ++k) acc += x[n * 4 + k] * W[k * H + h];
    node[i] = acc;
}

__global__ __launch_bounds__(256) void edge_embed(const float* __restrict__ ea,
                                                  const float* __restrict__ dW,
                                                  const float* __restrict__ db,
                                                  const float* __restrict__ tW,
                                                  const float* __restrict__ tb,
                                                  float* __restrict__ edge) {
    int i = blockIdx.x * blockDim.x + threadIdx.x;
    if (i >= EH) return;
    int e = i / H, h = i % H;
    float v;
    if (h < HHALF) v = ea[e * 2 + 0] * dW[h] + db[h];
    else           v = ea[e * 2 + 1] * tW[h - HHALF] + tb[h - HHALF];
    edge[i] = v;
}

// ---------------------------------------------------------------- fp32 GEMM
// C[M,N] = A[M,K] @ B[K,N] + bias[N].  64x64 tile, 4x4 per thread, K-tile 16.
#define TS 64
#define KT 16
__global__ __launch_bounds__(256) void gemm_bias(const float* __restrict__ A,
                                                 const float* __restrict__ B,
                                                 const float* __restrict__ bias,
                                                 float* __restrict__ C,
                                                 int M, int N, int K) {
    __shared__ float As[TS][KT + 1];
    __shared__ float Bs[KT][TS + 1];
    int tid = threadIdx.x;
    int tx = tid & 15, ty = tid >> 4;
    int r0 = blockIdx.y * TS, c0 = blockIdx.x * TS;
    float acc[4][4] = {};
    for (int kk = 0; kk < K; kk += KT) {
#pragma unroll
        for (int j = 0; j < 4; ++j) {
            int idx = tid + 256 * j;           // 0..1023
            int i = idx >> 4, k = idx & 15;
            int gr = r0 + i, gk = kk + k;
            As[i][k] = (gr < M && gk < K) ? A[(size_t)gr * K + gk] : 0.f;
        }
#pragma unroll
        for (int j = 0; j < 4; ++j) {
            int idx = tid + 256 * j;
            int k = idx >> 6, c = idx & 63;
            int gk = kk + k, gc = c0 + c;
            Bs[k][c] = (gk < K && gc < N) ? B[(size_t)gk * N + gc] : 0.f;
        }
        __syncthreads();
#pragma unroll
        for (int k = 0; k < KT; ++k) {
            float a[4], b[4];
#pragma unroll
            for (int m = 0; m < 4; ++m) a[m] = As[ty * 4 + m][k];
#pragma unroll
            for (int n = 0; n < 4; ++n) b[n] = Bs[k][tx * 4 + n];
#pragma unroll
            for (int m = 0; m < 4; ++m)
#pragma unroll
                for (int n = 0; n < 4; ++n) acc[m][n] += a[m] * b[n];
        }
        __syncthreads();
    }
#pragma unroll
    for (int m = 0; m < 4; ++m) {
        int gr = r0 + ty * 4 + m;
        if (gr >= M) break;
#pragma unroll
        for (int n = 0; n < 4; ++n) {
            int gc = c0 + tx * 4 + n;
            if (gc < N) C[(size_t)gr * N + gc] = acc[m][n] + bias[gc];
        }
    }
}

// ------------------------------------------------- gate += gathers, col stats
// gate[e][h] += nodeU[src[e]][h] + nodeU[dst[e]][h]
// accumulate per-column: sum(gate), sum(gate^2), sum(sigmoid(edge_old))
#define ROWS_PB_E 128
__global__ __launch_bounds__(256) void gate_gather_stats(float* __restrict__ gate,
                                                         const float* __restrict__ edge,
                                                         const float* __restrict__ nodeU,
                                                         const int* __restrict__ src,
                                                         const int* __restrict__ dst,
                                                         float* __restrict__ gsum,
                                                         float* __restrict__ gsumsq,
                                                         float* __restrict__ ssum) {
    __shared__ float s_g[H], s_g2[H], s_s[H];
    for (int h = threadIdx.x; h < H; h += blockDim.x) { s_g[h] = 0.f; s_g2[h] = 0.f; s_s[h] = 0.f; }
    __syncthreads();
    int e0 = blockIdx.x * ROWS_PB_E;
    int nrows = min(ROWS_PB_E, N_EDGES - e0);
    for (int idx = threadIdx.x; idx < nrows * H; idx += blockDim.x) {
        int e = e0 + idx / H, h = idx % H;
        size_t gi = (size_t)e * H + h;
        float g = gate[gi] + nodeU[src[e] * H + h] + nodeU[dst[e] * H + h];
        gate[gi] = g;
        atomicAdd(&s_g[h], g);
        atomicAdd(&s_g2[h], g * g);
        float sg = 1.f / (1.f + __expf(-edge[gi]));
        atomicAdd(&s_s[h], sg);
    }
    __syncthreads();
    for (int h = threadIdx.x; h < H; h += blockDim.x) {
        atomicAdd(&gsum[h], s_g[h]);
        atomicAdd(&gsumsq[h], s_g2[h]);
        atomicAdd(&ssum[h], s_s[h]);
    }
}

// ------------------------- BN(edge gate) + residual, message + scatter to agg
__global__ __launch_bounds__(256) void edge_finalize_msg(float* __restrict__ edge,
                                                         const float* __restrict__ gate,
                                                         const float* __restrict__ nodeV,
                                                         const int* __restrict__ src,
                                                         const int* __restrict__ dst,
                                                         const float* __restrict__ gsum,
                                                         const float* __restrict__ gsumsq,
                                                         const float* __restrict__ ssum,
                                                         const float* __restrict__ gamma,
                                                         const float* __restrict__ beta,
                                                         float* __restrict__ agg) {
    int i = blockIdx.x * blockDim.x + threadIdx.x;
    if (i >= EH) return;
    int e = i / H, h = i % H;
    const float invE = 1.f / N_EDGES;
    float mean = gsum[h] * invE;
    float var = fmaxf(gsumsq[h] * invE - mean * mean, 0.f);
    float rstd = rsqrtf(var + 1e-5f);
    float old = edge[i];
    float g = (gate[i] - mean) * rstd * gamma[h] + beta[h];
    edge[i] = old + fmaxf(g, 0.f);
    float sg = 1.f / (1.f + __expf(-old));
    float eta = sg / (ssum[h] + 1e-20f);
    float msg = eta * nodeV[src[e] * H + h];
    atomicAdd(&agg[dst[e] * H + h], msg);
}

// -------------------------------------------------------- node BN statistics
#define ROWS_PB_N 25
__global__ __launch_bounds__(256) void node_stats(const float* __restrict__ nodeUn,
                                                  const float* __restrict__ agg,
                                                  float* __restrict__ nsum,
                                                  float* __restrict__ nsumsq) {
    __shared__ float s1[H], s2[H];
    for (int h = threadIdx.x; h < H; h += blockDim.x) { s1[h] = 0.f; s2[h] = 0.f; }
    __syncthreads();
    int r0 = blockIdx.x * ROWS_PB_N;
    int nrows = min(ROWS_PB_N, N_NODES - r0);
    for (int idx = threadIdx.x; idx < nrows * H; idx += blockDim.x) {
        int r = r0 + idx / H, h = idx % H;
        float v = nodeUn[r * H + h] + agg[r * H + h];
        atomicAdd(&s1[h], v);
        atomicAdd(&s2[h], v * v);
    }
    __syncthreads();
    for (int h = threadIdx.x; h < H; h += blockDim.x) {
        atomicAdd(&nsum[h], s1[h]);
        atomicAdd(&nsumsq[h], s2[h]);
    }
}

__global__ __launch_bounds__(256) void node_update(float* __restrict__ node,
                                                   const float* __restrict__ nodeUn,
                                                   const float* __restrict__ agg,
                                                   const float* __restrict__ nsum,
                                                   const float* __restrict__ nsumsq,
                                                   const float* __restrict__ gamma,
                                                   const float* __restrict__ beta) {
    int i = blockIdx.x * blockDim.x + threadIdx.x;
    if (i >= NH) return;
    int h = i % H;
    const float invN = 1.f / N_NODES;
    float mean = nsum[h] * invN;
    float var = fmaxf(nsumsq[h] * invN - mean * mean, 0.f);
    float rstd = rsqrtf(var + 1e-5f);
    float g = (nodeUn[i] + agg[i] - mean) * rstd * gamma[h] + beta[h];
    node[i] += fmaxf(g, 0.f);
}

// ------------------------------------------------------- classifier + loss
__global__ __launch_bounds__(256) void classify_loss(const float* __restrict__ edge,
                                                     const float* __restrict__ clsW,
                                                     const float* __restrict__ clsb,
                                                     const int* __restrict__ src,
                                                     const int* __restrict__ dst,
                                                     const float* __restrict__ y,
                                                     float* __restrict__ out) {
    __shared__ float wl[4];
    int lane = threadIdx.x & 63;
    int wid = threadIdx.x >> 6;
    int gw = blockIdx.x * 4 + wid;  // 0..1999 global wave id
    float lsum = 0.f;
    for (int e = gw; e < N_EDGES; e += 2000) {
        float acc = 0.f;
        for (int h = lane; h < H; h += 64) acc += edge[(size_t)e * H + h] * clsW[h];
#pragma unroll
        for (int off = 32; off > 0; off >>= 1) acc += __shfl_down(acc, off, 64);
        if (lane == 0) {
            float z = acc + clsb[0];
            float p = 1.f / (1.f + __expf(-z));
            atomicAdd(&out[src[e] * N_NODES + dst[e]], p);
            float pc = fminf(fmaxf(p, 1e-7f), 1.f - 1e-7f);
            lsum += -(y[e] * __logf(pc) + (1.f - y[e]) * log1pf(-pc));
        }
    }
    if (lane == 0) wl[wid] = lsum;
    __syncthreads();
    if (threadIdx.x == 0) {
        float t = wl[0] + wl[1] + wl[2] + wl[3];
        atomicAdd(&out[N_NODES * N_NODES], t * (1.f / N_EDGES));
    }
}

// ---------------------------------------------------------------- launcher
extern "C" void kernel_launch(void* const* d_in, const int* in_sizes, int n_in,
                              void* d_out, int out_size, void* d_ws, size_t ws_size,
                              hipStream_t stream) {
    const float* x          = (const float*)d_in[0];
    const float* edge_attr  = (const float*)d_in[1];
    const int*   edge_index = (const int*)d_in[2];
    const float* y          = (const float*)d_in[3];
    const float* node_emb_W = (const float*)d_in[4];
    const float* node_emb_b = (const float*)d_in[5];
    const float* edge_d_W   = (const float*)d_in[6];
    const float* edge_d_b   = (const float*)d_in[7];
    const float* edge_t_W   = (const float*)d_in[8];
    const float* edge_t_b   = (const float*)d_in[9];
    const float* eU_W = (const float*)d_in[10];
    const float* eU_b = (const float*)d_in[11];
    const float* eW_W = (const float*)d_in[12];
    const float* eW_b = (const float*)d_in[13];
    const float* nU_W = (const float*)d_in[14];
    const float* nU_b = (const float*)d_in[15];
    const float* nV_W = (const float*)d_in[16];
    const float* nV_b = (const float*)d_in[17];
    const float* bn_e_g = (const float*)d_in[18];
    const float* bn_e_b = (const float*)d_in[19];
    const float* bn_n_g = (const float*)d_in[20];
    const float* bn_n_b = (const float*)d_in[21];
    const float* cls_W = (const float*)d_in[22];
    const float* cls_b = (const float*)d_in[23];

    const int* src = edge_index;            // row 0
    const int* dst = edge_index + N_EDGES;  // row 1

    float* ws     = (float*)d_ws;
    float* edge   = ws;                 // EH
    float* gate   = edge + EH;          // EH
    float* node   = gate + EH;          // NH
    float* nodeU  = node + NH;          // NH
    float* nodeV  = nodeU + NH;         // NH
    float* nodeUn = nodeV + NH;         // NH
    float* agg    = nodeUn + NH;        // NH
    float* stats  = agg + NH;           // 5*300 (contiguous after agg)
    float* gsum   = stats;
    float* gsumsq = stats + H;
    float* ssum   = stats + 2 * H;
    float* nsum   = stats + 3 * H;
    float* nsumsq = stats + 4 * H;

    float* out = (float*)d_out;

    // zero pred_adj + loss slot
    zero_buf<<<(N_NODES * N_NODES + 1 + 255) / 256, 256, 0, stream>>>(out, N_NODES * N_NODES + 1);

    node_embed<<<(NH + 255) / 256, 256, 0, stream>>>(x, node_emb_W, node_emb_b, node);
    edge_embed<<<(EH + 255) / 256, 256, 0, stream>>>(edge_attr, edge_d_W, edge_d_b,
                                                     edge_t_W, edge_t_b, edge);

    dim3 gN(5, (N_NODES + TS - 1) / TS);   // node gemms: 5 x 32
    dim3 gE(5, (N_EDGES + TS - 1) / TS);   // edge gemm:  5 x 500

    for (int l = 0; l < NLAYERS; ++l) {
        const float* eUW = eU_W + (size_t)l * H * H;
        const float* eUb = eU_b + l * H;
        const float* eWW = eW_W + (size_t)l * H * H;
        const float* eWb = eW_b + l * H;
        const float* nUW = nU_W + (size_t)l * H * H;
        const float* nUb = nU_b + l * H;
        const float* nVW = nV_W + (size_t)l * H * H;
        const float* nVb = nV_b + l * H;
        const float* geg = bn_e_g + l * H;
        const float* geb = bn_e_b + l * H;
        const float* gng = bn_n_g + l * H;
        const float* gnb = bn_n_b + l * H;

        // zero agg + all column stats (contiguous)
        zero_buf<<<(NH + 5 * H + 255) / 256, 256, 0, stream>>>(agg, NH + 5 * H);

        gemm_bias<<<gN, 256, 0, stream>>>(node, eUW, eUb, nodeU,  N_NODES, H, H);
        gemm_bias<<<gN, 256, 0, stream>>>(node, nVW, nVb, nodeV,  N_NODES, H, H);
        gemm_bias<<<gN, 256, 0, stream>>>(node, nUW, nUb, nodeUn, N_NODES, H, H);
        gemm_bias<<<gE, 256, 0, stream>>>(edge, eWW, eWb, gate,   N_EDGES, H, H);

        gate_gather_stats<<<N_EDGES / ROWS_PB_E, 256, 0, stream>>>(gate, edge, nodeU, src, dst,
                                                                   gsum, gsumsq, ssum);
        edge_finalize_msg<<<(EH + 255) / 256, 256, 0, stream>>>(edge, gate, nodeV, src, dst,
                                                                gsum, gsumsq, ssum, geg, geb, agg);
        node_stats<<<(N_NODES + ROWS_PB_N - 1) / ROWS_PB_N, 256, 0, stream>>>(nodeUn, agg, nsum, nsumsq);
        node_update<<<(NH + 255) / 256, 256, 0, stream>>>(node, nodeUn, agg, nsum, nsumsq, gng, gnb);
    }

    classify_loss<<<500, 256, 0, stream>>>(edge, cls_W, cls_b, src, dst, y, out);
}

// Round 2
// 6433.037 us; speedup vs baseline: 2.6798x; 2.6798x over previous
//
#include <hip/hip_runtime.h>
#include <hip/hip_bf16.h>
#include <math.h>

#define N_NODES 2000
#define N_EDGES 32000
#define H 300
#define HP 320            // padded H (K and N padded to 320 for MFMA)
#define NLAYERS 30
#define NH (N_NODES * H)     // 600000
#define EH (N_EDGES * H)     // 9600000
#define NODE_ROWS_PAD 2048
#define WMAT (HP * HP)       // 102400 elements per transposed weight matrix

typedef short bf16x8 __attribute__((ext_vector_type(8)));
typedef float f32x4 __attribute__((ext_vector_type(4)));
typedef __hip_bfloat16 bf16;

// ---------------------------------------------------------------- utilities
__global__ __launch_bounds__(256) void zero_buf(float* __restrict__ p, int n) {
    int i = blockIdx.x * blockDim.x + threadIdx.x;
    if (i < n) p[i] = 0.f;
}

// --------------------------------------------- weights -> bf16, transposed
// Wt_all[m][n][k] = W_m[k][n], zero-padded to 320x320.
// m: 0..29 eU, 30..59 eW, 60..89 nU, 90..119 nV
__global__ __launch_bounds__(256) void convert_weights(const float* __restrict__ eU,
                                                       const float* __restrict__ eW,
                                                       const float* __restrict__ nU,
                                                       const float* __restrict__ nV,
                                                       bf16* __restrict__ Wt) {
    long long idx = (long long)blockIdx.x * 256 + threadIdx.x;
    if (idx >= (long long)120 * WMAT) return;
    int m = (int)(idx / WMAT);
    int rem = (int)(idx % WMAT);
    int n = rem / HP, k = rem % HP;
    int grp = m / NLAYERS, l = m % NLAYERS;
    float v = 0.f;
    if (n < H && k < H) {
        const float* s = (grp == 0) ? eU : (grp == 1) ? eW : (grp == 2) ? nU : nV;
        v = s[(size_t)l * H * H + (size_t)k * H + n];
    }
    Wt[idx] = __float2bfloat16(v);
}

// ---------------------------------------------------------------- embeddings
__global__ __launch_bounds__(256) void node_embed(const float* __restrict__ x,
                                                  const float* __restrict__ W,
                                                  const float* __restrict__ b,
                                                  float* __restrict__ node,
                                                  bf16* __restrict__ node_bf) {
    int i = blockIdx.x * blockDim.x + threadIdx.x;
    if (i >= NH) return;
    int n = i / H, h = i % H;
    float acc = b[h];
#pragma unroll
    for (int k = 0; k < 4; ++k) acc += x[n * 4 + k] * W[k * H + h];
    node[i] = acc;
    node_bf[(size_t)n * HP + h] = __float2bfloat16(acc);
}

// edge embedding + sigmoid column-sum for layer 0 (ssum0)
#define ROWS_PB_E 32
__global__ __launch_bounds__(256) void edge_embed(const float* __restrict__ ea,
                                                  const float* __restrict__ dW,
                                                  const float* __restrict__ db,
                                                  const float* __restrict__ tW,
                                                  const float* __restrict__ tb,
                                                  float* __restrict__ edge,
                                                  bf16* __restrict__ edge_bf,
                                                  float* __restrict__ ssum0) {
    __shared__ float s_s[H];
    for (int h = threadIdx.x; h < H; h += 256) s_s[h] = 0.f;
    __syncthreads();
    int e0 = blockIdx.x * ROWS_PB_E;
    for (int idx = threadIdx.x; idx < ROWS_PB_E * H; idx += 256) {
        int e = e0 + idx / H, h = idx % H;
        float v;
        if (h < H / 2) v = ea[e * 2 + 0] * dW[h] + db[h];
        else           v = ea[e * 2 + 1] * tW[h - H / 2] + tb[h - H / 2];
        edge[(size_t)e * H + h] = v;
        edge_bf[(size_t)e * HP + h] = __float2bfloat16(v);
        atomicAdd(&s_s[h], 1.f / (1.f + __expf(-v)));
    }
    __syncthreads();
    for (int h = threadIdx.x; h < H; h += 256) atomicAdd(&ssum0[h], s_s[h]);
}

// ------------------------------------------------------------ MFMA core tile
// Block: 256 threads = 4 waves. Block tile 64 rows x 320 cols.
// Wave w: rows row0..row0+64, cols w*80..w*80+80 (5 col-tiles of 16).
// A [*, HP] bf16 row-major; Bt [HP n][HP k] bf16 (B transposed).
__device__ __forceinline__ void mfma_tile(const bf16* __restrict__ A,
                                          const bf16* __restrict__ Bt,
                                          int row0, int c0, int lane,
                                          f32x4 acc[4][5]) {
    int rlo = lane & 15, khi = lane >> 4;
#pragma unroll 2
    for (int ks = 0; ks < 10; ++ks) {
        int kk = ks * 32 + khi * 8;
        bf16x8 a[4], b[5];
#pragma unroll
        for (int rt = 0; rt < 4; ++rt)
            a[rt] = *(const bf16x8*)(A + (size_t)(row0 + rt * 16 + rlo) * HP + kk);
#pragma unroll
        for (int ct = 0; ct < 5; ++ct)
            b[ct] = *(const bf16x8*)(Bt + (size_t)(c0 + ct * 16 + rlo) * HP + kk);
#pragma unroll
        for (int rt = 0; rt < 4; ++rt)
#pragma unroll
            for (int ct = 0; ct < 5; ++ct)
                acc[rt][ct] = __builtin_amdgcn_mfma_f32_16x16x32_bf16(a[rt], b[ct], acc[rt][ct], 0, 0, 0);
    }
}

// --------------------------------------- node GEMMs (3 at once via grid.y)
__global__ __launch_bounds__(256) void gemm_node(const bf16* __restrict__ node_bf,
                                                 const bf16* __restrict__ Wt_all,
                                                 const float* __restrict__ eU_b,
                                                 const float* __restrict__ nV_b,
                                                 const float* __restrict__ nU_b,
                                                 int layer,
                                                 float* __restrict__ nodeU,
                                                 float* __restrict__ nodeV,
                                                 float* __restrict__ nodeUn) {
    int which = blockIdx.y;
    const bf16* Bt; const float* bias; float* out;
    if (which == 0)      { Bt = Wt_all + (size_t)(0 + layer) * WMAT;  bias = eU_b + layer * H; out = nodeU; }
    else if (which == 1) { Bt = Wt_all + (size_t)(90 + layer) * WMAT; bias = nV_b + layer * H; out = nodeV; }
    else                 { Bt = Wt_all + (size_t)(60 + layer) * WMAT; bias = nU_b + layer * H; out = nodeUn; }
    int lane = threadIdx.x & 63, wave = threadIdx.x >> 6;
    int row0 = blockIdx.x * 64, c0 = wave * 80;
    f32x4 acc[4][5];
#pragma unroll
    for (int rt = 0; rt < 4; ++rt)
#pragma unroll
        for (int ct = 0; ct < 5; ++ct) acc[rt][ct] = (f32x4)0.f;
    mfma_tile(node_bf, Bt, row0, c0, lane, acc);
    int rlo = lane & 15, rhi = lane >> 4;
#pragma unroll
    for (int ct = 0; ct < 5; ++ct) {
        int col = c0 + ct * 16 + rlo;
        if (col >= H) continue;
        float bv = bias[col];
#pragma unroll
        for (int rt = 0; rt < 4; ++rt)
#pragma unroll
            for (int j = 0; j < 4; ++j) {
                int r = row0 + rt * 16 + rhi * 4 + j;
                if (r < N_NODES) out[(size_t)r * H + col] = acc[rt][ct][j] + bv;
            }
    }
}

// ------------- edge gate GEMM fused with gathers + BN column stats
// gate = edge@eW + nodeU[src] + nodeU[dst]   (biases omitted: constant per
// column, exactly cancelled by BatchNorm)
__global__ __launch_bounds__(256) void gemm_edge(const bf16* __restrict__ edge_bf,
                                                 const bf16* __restrict__ Bt,
                                                 const float* __restrict__ nodeU,
                                                 const int* __restrict__ src,
                                                 const int* __restrict__ dst,
                                                 float* __restrict__ gate,
                                                 float* __restrict__ gsum,
                                                 float* __restrict__ gsumsq) {
    __shared__ float s_g[HP], s_g2[HP];
    for (int h = threadIdx.x; h < HP; h += 256) { s_g[h] = 0.f; s_g2[h] = 0.f; }
    int lane = threadIdx.x & 63, wave = threadIdx.x >> 6;
    int row0 = blockIdx.x * 64, c0 = wave * 80;
    f32x4 acc[4][5];
#pragma unroll
    for (int rt = 0; rt < 4; ++rt)
#pragma unroll
        for (int ct = 0; ct < 5; ++ct) acc[rt][ct] = (f32x4)0.f;
    mfma_tile(edge_bf, Bt, row0, c0, lane, acc);
    __syncthreads();   // LDS zeroed, acc ready
    int rlo = lane & 15, rhi = lane >> 4;
    float csum[5] = {0.f, 0.f, 0.f, 0.f, 0.f};
    float csq[5]  = {0.f, 0.f, 0.f, 0.f, 0.f};
#pragma unroll
    for (int rt = 0; rt < 4; ++rt)
#pragma unroll
        for (int j = 0; j < 4; ++j) {
            int r = row0 + rt * 16 + rhi * 4 + j;
            int se = src[r], de = dst[r];
#pragma unroll
            for (int ct = 0; ct < 5; ++ct) {
                int col = c0 + ct * 16 + rlo;
                if (col < H) {
                    float g = acc[rt][ct][j] + nodeU[(size_t)se * H + col] + nodeU[(size_t)de * H + col];
                    gate[(size_t)r * H + col] = g;
                    csum[ct] += g;
                    csq[ct] += g * g;
                }
            }
        }
#pragma unroll
    for (int ct = 0; ct < 5; ++ct) {
        int col = c0 + ct * 16 + rlo;
        if (col < H) {
            atomicAdd(&s_g[col], csum[ct]);
            atomicAdd(&s_g2[col], csq[ct]);
        }
    }
    __syncthreads();
    for (int h = threadIdx.x; h < H; h += 256) {
        atomicAdd(&gsum[h], s_g[h]);
        atomicAdd(&gsumsq[h], s_g2[h]);
    }
}

// -------- BN(gate)+residual -> edge (+bf16), message scatter, ssum_next
__global__ __launch_bounds__(256) void edge_finalize(float* __restrict__ edge,
                                                     bf16* __restrict__ edge_bf,
                                                     const float* __restrict__ gate,
                                                     const float* __restrict__ nodeV,
                                                     const int* __restrict__ src,
                                                     const int* __restrict__ dst,
                                                     const float* __restrict__ gsum,
                                                     const float* __restrict__ gsumsq,
                                                     const float* __restrict__ ssum_cur,
                                                     float* __restrict__ ssum_next,
                                                     const float* __restrict__ gamma,
                                                     const float* __restrict__ beta,
                                                     float* __restrict__ agg,
                                                     float* __restrict__ nstats /*nsum,nsumsq 600*/) {
    __shared__ float s_s[H];
    for (int h = threadIdx.x; h < H; h += 256) s_s[h] = 0.f;
    if (blockIdx.x == 0)
        for (int h = threadIdx.x; h < 2 * H; h += 256) nstats[h] = 0.f;
    __syncthreads();
    const float invE = 1.f / N_EDGES;
    int e0 = blockIdx.x * ROWS_PB_E;
    for (int idx = threadIdx.x; idx < ROWS_PB_E * H; idx += 256) {
        int e = e0 + idx / H, h = idx % H;
        size_t gi = (size_t)e * H + h;
        float mean = gsum[h] * invE;
        float var = fmaxf(gsumsq[h] * invE - mean * mean, 0.f);
        float rstd = rsqrtf(var + 1e-5f);
        float old = edge[gi];
        float g = (gate[gi] - mean) * rstd * gamma[h] + beta[h];
        float nv = old + fmaxf(g, 0.f);
        edge[gi] = nv;
        edge_bf[(size_t)e * HP + h] = __float2bfloat16(nv);
        atomicAdd(&s_s[h], 1.f / (1.f + __expf(-nv)));
        float sg = 1.f / (1.f + __expf(-old));
        float eta = sg / (ssum_cur[h] + 1e-20f);
        atomicAdd(&agg[(size_t)dst[e] * H + h], eta * nodeV[(size_t)src[e] * H + h]);
    }
    __syncthreads();
    for (int h = threadIdx.x; h < H; h += 256) atomicAdd(&ssum_next[h], s_s[h]);
}

// -------------------------------------------------------- node BN statistics
#define ROWS_PB_N 25
__global__ __launch_bounds__(256) void node_stats(const float* __restrict__ nodeUn,
                                                  const float* __restrict__ agg,
                                                  float* __restrict__ nsum,
                                                  float* __restrict__ nsumsq,
                                                  float* __restrict__ gstats /*gsum,gsumsq 600*/,
                                                  float* __restrict__ ssum_cur) {
    __shared__ float s1[H], s2[H];
    for (int h = threadIdx.x; h < H; h += 256) { s1[h] = 0.f; s2[h] = 0.f; }
    if (blockIdx.x == 0) {
        for (int h = threadIdx.x; h < 2 * H; h += 256) gstats[h] = 0.f;
        for (int h = threadIdx.x; h < H; h += 256) ssum_cur[h] = 0.f;
    }
    __syncthreads();
    int r0 = blockIdx.x * ROWS_PB_N;
    for (int idx = threadIdx.x; idx < ROWS_PB_N * H; idx += 256) {
        int r = r0 + idx / H, h = idx % H;
        float v = nodeUn[(size_t)r * H + h] + agg[(size_t)r * H + h];
        atomicAdd(&s1[h], v);
        atomicAdd(&s2[h], v * v);
    }
    __syncthreads();
    for (int h = threadIdx.x; h < H; h += 256) {
        atomicAdd(&nsum[h], s1[h]);
        atomicAdd(&nsumsq[h], s2[h]);
    }
}

// ------------------- node += relu(BN(nodeUn+agg)), write bf16, clear agg
__global__ __launch_bounds__(256) void node_update(float* __restrict__ node,
                                                   bf16* __restrict__ node_bf,
                                                   const float* __restrict__ nodeUn,
                                                   float* __restrict__ agg,
                                                   const float* __restrict__ nsum,
                                                   const float* __restrict__ nsumsq,
                                                   const float* __restrict__ gamma,
                                                   const float* __restrict__ beta) {
    int i = blockIdx.x * blockDim.x + threadIdx.x;
    if (i >= NH) return;
    int r = i / H, h = i % H;
    const float invN = 1.f / N_NODES;
    float mean = nsum[h] * invN;
    float var = fmaxf(nsumsq[h] * invN - mean * mean, 0.f);
    float rstd = rsqrtf(var + 1e-5f);
    float a = agg[i];
    agg[i] = 0.f;                       // ready for next layer
    float g = (nodeUn[i] + a - mean) * rstd * gamma[h] + beta[h];
    float nv = node[i] + fmaxf(g, 0.f);
    node[i] = nv;
    node_bf[(size_t)r * HP + h] = __float2bfloat16(nv);
}

// ------------------------------------------------------- classifier + loss
__global__ __launch_bounds__(256) void classify_loss(const float* __restrict__ edge,
                                                     const float* __restrict__ clsW,
                                                     const float* __restrict__ clsb,
                                                     const int* __restrict__ src,
                                                     const int* __restrict__ dst,
                                                     const float* __restrict__ y,
                                                     float* __restrict__ out) {
    __shared__ float wl[4];
    int lane = threadIdx.x & 63;
    int wid = threadIdx.x >> 6;
    int gw = blockIdx.x * 4 + wid;
    float lsum = 0.f;
    for (int e = gw; e < N_EDGES; e += 2000) {
        float acc = 0.f;
        for (int h = lane; h < H; h += 64) acc += edge[(size_t)e * H + h] * clsW[h];
#pragma unroll
        for (int off = 32; off > 0; off >>= 1) acc += __shfl_down(acc, off, 64);
        if (lane == 0) {
            float z = acc + clsb[0];
            float p = 1.f / (1.f + __expf(-z));
            atomicAdd(&out[(size_t)src[e] * N_NODES + dst[e]], p);
            float pc = fminf(fmaxf(p, 1e-7f), 1.f - 1e-7f);
            lsum += -(y[e] * __logf(pc) + (1.f - y[e]) * log1pf(-pc));
        }
    }
    if (lane == 0) wl[wid] = lsum;
    __syncthreads();
    if (threadIdx.x == 0) {
        float t = wl[0] + wl[1] + wl[2] + wl[3];
        atomicAdd(&out[(size_t)N_NODES * N_NODES], t * (1.f / N_EDGES));
    }
}

// ---------------------------------------------------------------- launcher
extern "C" void kernel_launch(void* const* d_in, const int* in_sizes, int n_in,
                              void* d_out, int out_size, void* d_ws, size_t ws_size,
                              hipStream_t stream) {
    const float* x          = (const float*)d_in[0];
    const float* edge_attr  = (const float*)d_in[1];
    const int*   edge_index = (const int*)d_in[2];
    const float* y          = (const float*)d_in[3];
    const float* node_emb_W = (const float*)d_in[4];
    const float* node_emb_b = (const float*)d_in[5];
    const float* edge_d_W   = (const float*)d_in[6];
    const float* edge_d_b   = (const float*)d_in[7];
    const float* edge_t_W   = (const float*)d_in[8];
    const float* edge_t_b   = (const float*)d_in[9];
    const float* eU_W = (const float*)d_in[10];
    const float* eU_b = (const float*)d_in[11];
    const float* eW_W = (const float*)d_in[12];
    const float* nU_W = (const float*)d_in[14];
    const float* nU_b = (const float*)d_in[15];
    const float* nV_W = (const float*)d_in[16];
    const float* nV_b = (const float*)d_in[17];
    const float* bn_e_g = (const float*)d_in[18];
    const float* bn_e_b = (const float*)d_in[19];
    const float* bn_n_g = (const float*)d_in[20];
    const float* bn_n_b = (const float*)d_in[21];
    const float* cls_W = (const float*)d_in[22];
    const float* cls_b = (const float*)d_in[23];

    const int* src = edge_index;
    const int* dst = edge_index + N_EDGES;

    float* ws     = (float*)d_ws;
    float* edge   = ws;                  // EH
    float* gate   = edge + EH;           // EH
    float* node   = gate + EH;           // NH
    float* nodeU  = node + NH;           // NH
    float* nodeV  = nodeU + NH;          // NH
    float* nodeUn = nodeV + NH;          // NH
    float* agg    = nodeUn + NH;         // NH   <-- zero region starts here
    float* stats  = agg + NH;            // 8*H
    float* gsum   = stats;               // 300
    float* gsumsq = stats + H;           // 300
    float* nsum   = stats + 2 * H;       // 300
    float* nsumsq = stats + 3 * H;       // 300
    float* ssum   = stats + 4 * H;       // 2 x 300 ping-pong
    bf16* node_bf = (bf16*)(stats + 8 * H);            // 2048*320 bf16
    bf16* edge_bf = node_bf + (size_t)NODE_ROWS_PAD * HP; // 32000*320 bf16
    bf16* Wt_all  = edge_bf + (size_t)N_EDGES * HP;    // 120*102400 bf16

    float* out = (float*)d_out;

    // zeroing: out (pred_adj + loss), and [agg | stats | node_bf | edge_bf]
    int zlen = NH + 8 * H + (NODE_ROWS_PAD * HP + N_EDGES * HP) / 2;
    zero_buf<<<(N_NODES * N_NODES + 1 + 255) / 256, 256, 0, stream>>>(out, N_NODES * N_NODES + 1);
    zero_buf<<<(zlen + 255) / 256, 256, 0, stream>>>(agg, zlen);

    convert_weights<<<(120 * WMAT + 255) / 256, 256, 0, stream>>>(eU_W, eW_W, nU_W, nV_W, Wt_all);
    node_embed<<<(NH + 255) / 256, 256, 0, stream>>>(x, node_emb_W, node_emb_b, node, node_bf);
    edge_embed<<<N_EDGES / ROWS_PB_E, 256, 0, stream>>>(edge_attr, edge_d_W, edge_d_b,
                                                        edge_t_W, edge_t_b, edge, edge_bf, ssum);

    dim3 gN(32, 3);   // node gemms
    for (int l = 0; l < NLAYERS; ++l) {
        float* ssum_cur  = ssum + (l & 1) * H;
        float* ssum_next = ssum + ((l + 1) & 1) * H;
        const bf16* BtE = Wt_all + (size_t)(30 + l) * WMAT;

        gemm_node<<<gN, 256, 0, stream>>>(node_bf, Wt_all, eU_b, nV_b, nU_b, l,
                                          nodeU, nodeV, nodeUn);
        gemm_edge<<<N_EDGES / 64, 256, 0, stream>>>(edge_bf, BtE, nodeU, src, dst,
                                                    gate, gsum, gsumsq);
        edge_finalize<<<N_EDGES / ROWS_PB_E, 256, 0, stream>>>(edge, edge_bf, gate, nodeV,
                                                               src, dst, gsum, gsumsq,
                                                               ssum_cur, ssum_next,
                                                               bn_e_g + l * H, bn_e_b + l * H,
                                                               agg, nsum);
        node_stats<<<(N_NODES + ROWS_PB_N - 1) / ROWS_PB_N, 256, 0, stream>>>(nodeUn, agg, nsum, nsumsq,
                                                                              gsum, ssum_cur);
        node_update<<<(NH + 255) / 256, 256, 0, stream>>>(node, node_bf, nodeUn, agg,
                                                          nsum, nsumsq,
                                                          bn_n_g + l * H, bn_n_b + l * H);
    }

    classify_loss<<<500, 256, 0, stream>>>(edge, cls_W, cls_b, src, dst, y, out);
}

// Round 3
// 4949.501 us; speedup vs baseline: 3.4831x; 1.2997x over previous
//
#include <hip/hip_runtime.h>
#include <hip/hip_bf16.h>
#include <math.h>

#define N_NODES 2000
#define N_EDGES 32000
#define H 300
#define CH 75             // H/4 float4 chunks per row
#define HP 320            // padded H for MFMA K/N
#define NLAYERS 30
#define NH (N_NODES * H)     // 600000
#define EH (N_EDGES * H)     // 9600000
#define NODE_ROWS_PAD 2048
#define WMAT (HP * HP)

typedef short bf16x8 __attribute__((ext_vector_type(8)));
typedef float f32x4 __attribute__((ext_vector_type(4)));
typedef __hip_bfloat16 bf16;

__device__ __forceinline__ float sigm(float x) { return 1.f / (1.f + __expf(-x)); }

// ---------------------------------------------------------------- utilities
__global__ __launch_bounds__(256) void zero_buf(float* __restrict__ p, int n) {
    int i = blockIdx.x * blockDim.x + threadIdx.x;
    if (i < n) p[i] = 0.f;
}

// --------------------------------------------- weights -> bf16, transposed
__global__ __launch_bounds__(256) void convert_weights(const float* __restrict__ eU,
                                                       const float* __restrict__ eW,
                                                       const float* __restrict__ nU,
                                                       const float* __restrict__ nV,
                                                       bf16* __restrict__ Wt) {
    long long idx = (long long)blockIdx.x * 256 + threadIdx.x;
    if (idx >= (long long)120 * WMAT) return;
    int m = (int)(idx / WMAT);
    int rem = (int)(idx % WMAT);
    int n = rem / HP, k = rem % HP;
    int grp = m / NLAYERS, l = m % NLAYERS;
    float v = 0.f;
    if (n < H && k < H) {
        const float* s = (grp == 0) ? eU : (grp == 1) ? eW : (grp == 2) ? nU : nV;
        v = s[(size_t)l * H * H + (size_t)k * H + n];
    }
    Wt[idx] = __float2bfloat16(v);
}

// ------------------------------------------------------------- CSR by dst
__global__ __launch_bounds__(256) void csr_hist(const int* __restrict__ dst,
                                                int* __restrict__ counts) {
    int i = blockIdx.x * 256 + threadIdx.x;
    if (i < N_EDGES) atomicAdd(&counts[dst[i]], 1);
}

__global__ __launch_bounds__(256) void csr_scan(const int* __restrict__ counts,
                                                int* __restrict__ offs,
                                                int* __restrict__ woff) {
    __shared__ int part[256];
    int t = threadIdx.x;
    int base = t * 8;
    int local[8];
    int s = 0;
#pragma unroll
    for (int j = 0; j < 8; ++j) {
        int c = (base + j < N_NODES) ? counts[base + j] : 0;
        local[j] = s;
        s += c;
    }
    part[t] = s;
    __syncthreads();
    for (int off = 1; off < 256; off <<= 1) {
        int v = (t >= off) ? part[t - off] : 0;
        __syncthreads();
        part[t] += v;
        __syncthreads();
    }
    int pre = (t == 0) ? 0 : part[t - 1];
#pragma unroll
    for (int j = 0; j < 8; ++j) {
        int idx = base + j;
        if (idx < N_NODES) { int v = pre + local[j]; offs[idx] = v; woff[idx] = v; }
    }
    if (t == 255) offs[N_NODES] = part[255];
}

__global__ __launch_bounds__(256) void csr_scatter(const int* __restrict__ dst,
                                                   int* __restrict__ woff,
                                                   int* __restrict__ eidx) {
    int i = blockIdx.x * 256 + threadIdx.x;
    if (i < N_EDGES) {
        int p = atomicAdd(&woff[dst[i]], 1);
        eidx[p] = i;
    }
}

// ---------------------------------------------------------------- embeddings
__global__ __launch_bounds__(256) void node_embed(const float* __restrict__ x,
                                                  const float* __restrict__ W,
                                                  const float* __restrict__ b,
                                                  float* __restrict__ node,
                                                  bf16* __restrict__ node_bf) {
    int i = blockIdx.x * blockDim.x + threadIdx.x;
    if (i >= NH) return;
    int n = i / H, h = i % H;
    float acc = b[h];
#pragma unroll
    for (int k = 0; k < 4; ++k) acc += x[n * 4 + k] * W[k * H + h];
    node[i] = acc;
    node_bf[(size_t)n * HP + h] = __float2bfloat16(acc);
}

#define ROWS_PB_E 32
__global__ __launch_bounds__(256) void edge_embed(const float* __restrict__ ea,
                                                  const float* __restrict__ dW,
                                                  const float* __restrict__ db,
                                                  const float* __restrict__ tW,
                                                  const float* __restrict__ tb,
                                                  float* __restrict__ edge,
                                                  bf16* __restrict__ edge_bf,
                                                  float* __restrict__ ssum0) {
    __shared__ float s_s[H];
    for (int h = threadIdx.x; h < H; h += 256) s_s[h] = 0.f;
    __syncthreads();
    int e0 = blockIdx.x * ROWS_PB_E;
    for (int idx = threadIdx.x; idx < ROWS_PB_E * H; idx += 256) {
        int e = e0 + idx / H, h = idx % H;
        float v;
        if (h < H / 2) v = ea[e * 2 + 0] * dW[h] + db[h];
        else           v = ea[e * 2 + 1] * tW[h - H / 2] + tb[h - H / 2];
        edge[(size_t)e * H + h] = v;
        bf16 bv = __float2bfloat16(v);
        edge_bf[(size_t)e * HP + h] = bv;
        atomicAdd(&s_s[h], sigm(__bfloat162float(bv)));
    }
    __syncthreads();
    for (int h = threadIdx.x; h < H; h += 256) atomicAdd(&ssum0[h], s_s[h]);
}

// ------------------------------------------------------------ MFMA core tile
__device__ __forceinline__ void mfma_tile(const bf16* __restrict__ A,
                                          const bf16* __restrict__ Bt,
                                          int row0, int c0, int lane,
                                          f32x4 acc[4][5]) {
    int rlo = lane & 15, khi = lane >> 4;
#pragma unroll 2
    for (int ks = 0; ks < 10; ++ks) {
        int kk = ks * 32 + khi * 8;
        bf16x8 a[4], b[5];
#pragma unroll
        for (int rt = 0; rt < 4; ++rt)
            a[rt] = *(const bf16x8*)(A + (size_t)(row0 + rt * 16 + rlo) * HP + kk);
#pragma unroll
        for (int ct = 0; ct < 5; ++ct)
            b[ct] = *(const bf16x8*)(Bt + (size_t)(c0 + ct * 16 + rlo) * HP + kk);
#pragma unroll
        for (int rt = 0; rt < 4; ++rt)
#pragma unroll
            for (int ct = 0; ct < 5; ++ct)
                acc[rt][ct] = __builtin_amdgcn_mfma_f32_16x16x32_bf16(a[rt], b[ct], acc[rt][ct], 0, 0, 0);
    }
}

// --------------------------------------- node GEMMs (3 at once via grid.y)
__global__ __launch_bounds__(256) void gemm_node(const bf16* __restrict__ node_bf,
                                                 const bf16* __restrict__ Wt_all,
                                                 const float* __restrict__ eU_b,
                                                 const float* __restrict__ nV_b,
                                                 const float* __restrict__ nU_b,
                                                 int layer,
                                                 float* __restrict__ nodeU,
                                                 float* __restrict__ nodeV,
                                                 float* __restrict__ nodeUn) {
    int which = blockIdx.y;
    const bf16* Bt; const float* bias; float* out;
    if (which == 0)      { Bt = Wt_all + (size_t)(0 + layer) * WMAT;  bias = eU_b + layer * H; out = nodeU; }
    else if (which == 1) { Bt = Wt_all + (size_t)(90 + layer) * WMAT; bias = nV_b + layer * H; out = nodeV; }
    else                 { Bt = Wt_all + (size_t)(60 + layer) * WMAT; bias = nU_b + layer * H; out = nodeUn; }
    int lane = threadIdx.x & 63, wave = threadIdx.x >> 6;
    int row0 = blockIdx.x * 64, c0 = wave * 80;
    f32x4 acc[4][5];
#pragma unroll
    for (int rt = 0; rt < 4; ++rt)
#pragma unroll
        for (int ct = 0; ct < 5; ++ct) acc[rt][ct] = (f32x4)0.f;
    mfma_tile(node_bf, Bt, row0, c0, lane, acc);
    int rlo = lane & 15, rhi = lane >> 4;
#pragma unroll
    for (int ct = 0; ct < 5; ++ct) {
        int col = c0 + ct * 16 + rlo;
        if (col >= H) continue;
        float bv = bias[col];
#pragma unroll
        for (int rt = 0; rt < 4; ++rt)
#pragma unroll
            for (int j = 0; j < 4; ++j) {
                int r = row0 + rt * 16 + rhi * 4 + j;
                if (r < N_NODES) out[(size_t)r * H + col] = acc[rt][ct][j] + bv;
            }
    }
}

// ------------- edge gate GEMM fused with gathers + BN column stats (bf16 out)
__global__ __launch_bounds__(256) void gemm_edge(const bf16* __restrict__ edge_bf,
                                                 const bf16* __restrict__ Bt,
                                                 const float* __restrict__ nodeU,
                                                 const int* __restrict__ src,
                                                 const int* __restrict__ dst,
                                                 bf16* __restrict__ gate_bf,
                                                 float* __restrict__ gsum,
                                                 float* __restrict__ gsumsq,
                                                 float* __restrict__ nstats) {
    __shared__ float s_g[HP], s_g2[HP];
    for (int h = threadIdx.x; h < HP; h += 256) { s_g[h] = 0.f; s_g2[h] = 0.f; }
    if (blockIdx.x == 0)
        for (int i = threadIdx.x; i < 2 * H; i += 256) nstats[i] = 0.f;  // zero nsum/nsumsq
    int lane = threadIdx.x & 63, wave = threadIdx.x >> 6;
    int row0 = blockIdx.x * 64, c0 = wave * 80;
    f32x4 acc[4][5];
#pragma unroll
    for (int rt = 0; rt < 4; ++rt)
#pragma unroll
        for (int ct = 0; ct < 5; ++ct) acc[rt][ct] = (f32x4)0.f;
    mfma_tile(edge_bf, Bt, row0, c0, lane, acc);
    __syncthreads();
    int rlo = lane & 15, rhi = lane >> 4;
    float csum[5] = {0.f, 0.f, 0.f, 0.f, 0.f};
    float csq[5]  = {0.f, 0.f, 0.f, 0.f, 0.f};
#pragma unroll
    for (int rt = 0; rt < 4; ++rt)
#pragma unroll
        for (int j = 0; j < 4; ++j) {
            int r = row0 + rt * 16 + rhi * 4 + j;
            int se = src[r], de = dst[r];
#pragma unroll
            for (int ct = 0; ct < 5; ++ct) {
                int col = c0 + ct * 16 + rlo;
                if (col < H) {
                    float g = acc[rt][ct][j] + nodeU[(size_t)se * H + col] + nodeU[(size_t)de * H + col];
                    gate_bf[(size_t)r * H + col] = __float2bfloat16(g);
                    csum[ct] += g;
                    csq[ct] += g * g;
                }
            }
        }
#pragma unroll
    for (int ct = 0; ct < 5; ++ct) {
        int col = c0 + ct * 16 + rlo;
        if (col < H) {
            atomicAdd(&s_g[col], csum[ct]);
            atomicAdd(&s_g2[col], csq[ct]);
        }
    }
    __syncthreads();
    for (int h = threadIdx.x; h < H; h += 256) {
        atomicAdd(&gsum[h], s_g[h]);
        atomicAdd(&gsumsq[h], s_g2[h]);
    }
}

// ------------- CSR gather: aggv[n] = nodeUn[n] + (Σ sigma(edge)·nodeV[src]) / ssum
__global__ __launch_bounds__(256) void node_msg(const bf16* __restrict__ edge_bf,
                                                const float* __restrict__ nodeV,
                                                const float* __restrict__ nodeUn,
                                                const int* __restrict__ src,
                                                const int* __restrict__ offs,
                                                const int* __restrict__ eidx,
                                                const float* __restrict__ ssum_cur,
                                                float* __restrict__ ssum_zero,
                                                float* __restrict__ aggv) {
    int n = blockIdx.x;
    int t = threadIdx.x;
    if (n == 0)
        for (int i = t; i < H; i += 256) ssum_zero[i] = 0.f;  // prep next layer's ssum
    int h0 = t;
    int h1 = 256 + t;           // valid if t < 44
    float a0 = 0.f, a1 = 0.f;
    int beg = offs[n], end = offs[n + 1];
    for (int i = beg; i < end; ++i) {
        int e = eidx[i];
        int s = src[e];
        const bf16* er = edge_bf + (size_t)e * HP;
        const float* vr = nodeV + (size_t)s * H;
        a0 += sigm(__bfloat162float(er[h0])) * vr[h0];
        if (t < 44) a1 += sigm(__bfloat162float(er[h1])) * vr[h1];
    }
    size_t nb = (size_t)n * H;
    aggv[nb + h0] = nodeUn[nb + h0] + a0 / (ssum_cur[h0] + 1e-20f);
    if (t < 44) aggv[nb + h1] = nodeUn[nb + h1] + a1 / (ssum_cur[h1] + 1e-20f);
}

// -------- BN(gate)+residual -> edge (+bf16), ssum_next (vectorized, no scatter)
#define EF_ROWS 64
__global__ __launch_bounds__(256) void edge_finalize(float* __restrict__ edge,
                                                     bf16* __restrict__ edge_bf,
                                                     const bf16* __restrict__ gate_bf,
                                                     const float* __restrict__ gsum,
                                                     const float* __restrict__ gsumsq,
                                                     const float* __restrict__ gamma,
                                                     const float* __restrict__ beta,
                                                     float* __restrict__ ssum_next) {
    __shared__ float s_s[H];
    int t = threadIdx.x;
    for (int i = t; i < H; i += 256) s_s[i] = 0.f;
    __syncthreads();
    int hc = t % 80, rgrp = t / 80;
    bool act = (hc < CH) && (rgrp < 3);
    float ss[4] = {0.f, 0.f, 0.f, 0.f};
    int col0 = hc * 4;
    if (act) {
        const float invE = 1.f / N_EDGES;
        float4 s4 = *(const float4*)(gsum + col0);
        float4 q4 = *(const float4*)(gsumsq + col0);
        float4 g4 = *(const float4*)(gamma + col0);
        float4 b4 = *(const float4*)(beta + col0);
        float sc[4], of[4];
        const float* s4p = (const float*)&s4; const float* q4p = (const float*)&q4;
        const float* g4p = (const float*)&g4; const float* b4p = (const float*)&b4;
#pragma unroll
        for (int j = 0; j < 4; ++j) {
            float mean = s4p[j] * invE;
            float var = fmaxf(q4p[j] * invE - mean * mean, 0.f);
            float rstd = rsqrtf(var + 1e-5f);
            float scale = rstd * g4p[j];
            sc[j] = scale;
            of[j] = b4p[j] - mean * scale;
        }
        int e0 = blockIdx.x * EF_ROWS;
        for (int r = rgrp; r < EF_ROWS; r += 3) {
            int e = e0 + r;
            float4 ev = *(const float4*)(edge + (size_t)e * H + col0);
            const float* evp = (const float*)&ev;
            union { ushort4 u; bf16 b[4]; } gv, ob;
            gv.u = *(const ushort4*)(gate_bf + (size_t)e * H + col0);
            float nv[4];
#pragma unroll
            for (int j = 0; j < 4; ++j) {
                float g = __bfloat162float(gv.b[j]);
                float val = fmaxf(fmaf(g, sc[j], of[j]), 0.f);
                nv[j] = evp[j] + val;
                ob.b[j] = __float2bfloat16(nv[j]);
                ss[j] += sigm(__bfloat162float(ob.b[j]));
            }
            *(float4*)(edge + (size_t)e * H + col0) = make_float4(nv[0], nv[1], nv[2], nv[3]);
            *(ushort4*)(edge_bf + (size_t)e * HP + col0) = ob.u;
        }
#pragma unroll
        for (int j = 0; j < 4; ++j) atomicAdd(&s_s[col0 + j], ss[j]);
    }
    __syncthreads();
    for (int i = t; i < H; i += 256) atomicAdd(&ssum_next[i], s_s[i]);
}

// -------------------------------------------------------- node BN statistics
__global__ __launch_bounds__(256) void node_stats(const float* __restrict__ aggv,
                                                  float* __restrict__ nsum,
                                                  float* __restrict__ nsumsq) {
    __shared__ float s1[H], s2[H];
    int t = threadIdx.x;
    for (int i = t; i < H; i += 256) { s1[i] = 0.f; s2[i] = 0.f; }
    __syncthreads();
    int base = blockIdx.x * 1875;   // 25 rows x 75 chunks
    for (int i = t; i < 1875; i += 256) {
        int gc = base + i;
        float4 v = ((const float4*)aggv)[gc];
        const float* vp = (const float*)&v;
        int col = (gc % CH) * 4;
#pragma unroll
        for (int j = 0; j < 4; ++j) {
            atomicAdd(&s1[col + j], vp[j]);
            atomicAdd(&s2[col + j], vp[j] * vp[j]);
        }
    }
    __syncthreads();
    for (int i = t; i < H; i += 256) {
        atomicAdd(&nsum[i], s1[i]);
        atomicAdd(&nsumsq[i], s2[i]);
    }
}

// ------------------- node += relu(BN(aggv)), write bf16; zero gsum/gsumsq
__global__ __launch_bounds__(256) void node_update(float* __restrict__ node,
                                                   bf16* __restrict__ node_bf,
                                                   const float* __restrict__ aggv,
                                                   const float* __restrict__ nsum,
                                                   const float* __restrict__ nsumsq,
                                                   const float* __restrict__ gamma,
                                                   const float* __restrict__ beta,
                                                   float* __restrict__ gstats) {
    int c = blockIdx.x * 256 + threadIdx.x;
    if (blockIdx.x == 0)
        for (int i = threadIdx.x; i < 2 * H; i += 256) gstats[i] = 0.f;  // zero gsum/gsumsq
    if (c >= NH / 4) return;
    int n = c / CH, hc = c % CH, col0 = hc * 4;
    const float invN = 1.f / N_NODES;
    float4 v4 = ((const float4*)aggv)[c];
    float4 s4 = *(const float4*)(nsum + col0);
    float4 q4 = *(const float4*)(nsumsq + col0);
    float4 g4 = *(const float4*)(gamma + col0);
    float4 b4 = *(const float4*)(beta + col0);
    float4 nd = ((const float4*)node)[c];
    const float* v4p = (const float*)&v4; const float* s4p = (const float*)&s4;
    const float* q4p = (const float*)&q4; const float* g4p = (const float*)&g4;
    const float* b4p = (const float*)&b4; const float* ndp = (const float*)&nd;
    union { ushort4 u; bf16 b[4]; } ob;
    float out[4];
#pragma unroll
    for (int j = 0; j < 4; ++j) {
        float mean = s4p[j] * invN;
        float var = fmaxf(q4p[j] * invN - mean * mean, 0.f);
        float rstd = rsqrtf(var + 1e-5f);
        float g = (v4p[j] - mean) * rstd * g4p[j] + b4p[j];
        out[j] = ndp[j] + fmaxf(g, 0.f);
        ob.b[j] = __float2bfloat16(out[j]);
    }
    ((float4*)node)[c] = make_float4(out[0], out[1], out[2], out[3]);
    *(ushort4*)(node_bf + (size_t)n * HP + col0) = ob.u;
}

// ------------------------------------------------------- classifier + loss
__global__ __launch_bounds__(256) void classify_loss(const float* __restrict__ edge,
                                                     const float* __restrict__ clsW,
                                                     const float* __restrict__ clsb,
                                                     const int* __restrict__ src,
                                                     const int* __restrict__ dst,
                                                     const float* __restrict__ y,
                                                     float* __restrict__ out) {
    __shared__ float wl[4];
    int lane = threadIdx.x & 63;
    int wid = threadIdx.x >> 6;
    int gw = blockIdx.x * 4 + wid;
    float lsum = 0.f;
    for (int e = gw; e < N_EDGES; e += 2000) {
        float acc = 0.f;
        for (int h = lane; h < H; h += 64) acc += edge[(size_t)e * H + h] * clsW[h];
#pragma unroll
        for (int off = 32; off > 0; off >>= 1) acc += __shfl_down(acc, off, 64);
        if (lane == 0) {
            float z = acc + clsb[0];
            float p = 1.f / (1.f + __expf(-z));
            atomicAdd(&out[(size_t)src[e] * N_NODES + dst[e]], p);
            float pc = fminf(fmaxf(p, 1e-7f), 1.f - 1e-7f);
            lsum += -(y[e] * __logf(pc) + (1.f - y[e]) * log1pf(-pc));
        }
    }
    if (lane == 0) wl[wid] = lsum;
    __syncthreads();
    if (threadIdx.x == 0) {
        float t = wl[0] + wl[1] + wl[2] + wl[3];
        atomicAdd(&out[(size_t)N_NODES * N_NODES], t * (1.f / N_EDGES));
    }
}

// ---------------------------------------------------------------- launcher
extern "C" void kernel_launch(void* const* d_in, const int* in_sizes, int n_in,
                              void* d_out, int out_size, void* d_ws, size_t ws_size,
                              hipStream_t stream) {
    const float* x          = (const float*)d_in[0];
    const float* edge_attr  = (const float*)d_in[1];
    const int*   edge_index = (const int*)d_in[2];
    const float* y          = (const float*)d_in[3];
    const float* node_emb_W = (const float*)d_in[4];
    const float* node_emb_b = (const float*)d_in[5];
    const float* edge_d_W   = (const float*)d_in[6];
    const float* edge_d_b   = (const float*)d_in[7];
    const float* edge_t_W   = (const float*)d_in[8];
    const float* edge_t_b   = (const float*)d_in[9];
    const float* eU_W = (const float*)d_in[10];
    const float* eU_b = (const float*)d_in[11];
    const float* eW_W = (const float*)d_in[12];
    const float* nU_W = (const float*)d_in[14];
    const float* nU_b = (const float*)d_in[15];
    const float* nV_W = (const float*)d_in[16];
    const float* nV_b = (const float*)d_in[17];
    const float* bn_e_g = (const float*)d_in[18];
    const float* bn_e_b = (const float*)d_in[19];
    const float* bn_n_g = (const float*)d_in[20];
    const float* bn_n_b = (const float*)d_in[21];
    const float* cls_W = (const float*)d_in[22];
    const float* cls_b = (const float*)d_in[23];

    const int* src = edge_index;
    const int* dst = edge_index + N_EDGES;

    float* ws     = (float*)d_ws;
    float* edge   = ws;                  // EH
    float* node   = edge + EH;           // NH
    float* nodeU  = node + NH;           // NH
    float* nodeV  = nodeU + NH;          // NH
    float* nodeUn = nodeV + NH;          // NH
    float* aggv   = nodeUn + NH;         // NH
    float* stats  = aggv + NH;           // 2048 floats
    float* gsum   = stats;               // 300
    float* gsumsq = stats + H;           // 300
    float* nsum   = stats + 2 * H;       // 300
    float* nsumsq = stats + 3 * H;       // 300
    float* ssum   = stats + 4 * H;       // 2 x 300 ping-pong
    bf16* node_bf = (bf16*)(stats + 2048);               // 2048*320
    bf16* edge_bf = node_bf + (size_t)NODE_ROWS_PAD * HP; // 32000*320
    bf16* gate_bf = edge_bf + (size_t)N_EDGES * HP;       // 32000*300
    bf16* Wt_all  = gate_bf + (size_t)N_EDGES * H;        // 120*102400
    int* csr_counts = (int*)(Wt_all + (size_t)120 * WMAT); // 2048
    int* csr_offs   = csr_counts + 2048;                   // 2048 (2001 used)
    int* csr_woff   = csr_offs + 2048;                     // 2048
    int* csr_eidx   = csr_woff + 2048;                     // 32000

    float* out = (float*)d_out;

    // zero: out, [stats | node_bf | edge_bf], csr_counts
    int zlen = 2048 + (NODE_ROWS_PAD * HP + N_EDGES * HP) / 2;
    zero_buf<<<(N_NODES * N_NODES + 1 + 255) / 256, 256, 0, stream>>>(out, N_NODES * N_NODES + 1);
    zero_buf<<<(zlen + 255) / 256, 256, 0, stream>>>(stats, zlen);
    zero_buf<<<8, 256, 0, stream>>>((float*)csr_counts, 2048);

    convert_weights<<<(120 * WMAT + 255) / 256, 256, 0, stream>>>(eU_W, eW_W, nU_W, nV_W, Wt_all);
    csr_hist<<<(N_EDGES + 255) / 256, 256, 0, stream>>>(dst, csr_counts);
    csr_scan<<<1, 256, 0, stream>>>(csr_counts, csr_offs, csr_woff);
    csr_scatter<<<(N_EDGES + 255) / 256, 256, 0, stream>>>(dst, csr_woff, csr_eidx);
    node_embed<<<(NH + 255) / 256, 256, 0, stream>>>(x, node_emb_W, node_emb_b, node, node_bf);
    edge_embed<<<N_EDGES / ROWS_PB_E, 256, 0, stream>>>(edge_attr, edge_d_W, edge_d_b,
                                                        edge_t_W, edge_t_b, edge, edge_bf, ssum);

    dim3 gN(32, 3);
    for (int l = 0; l < NLAYERS; ++l) {
        float* ssum_cur = ssum + (l & 1) * H;
        float* ssum_nxt = ssum + ((l + 1) & 1) * H;
        const bf16* BtE = Wt_all + (size_t)(30 + l) * WMAT;

        gemm_node<<<gN, 256, 0, stream>>>(node_bf, Wt_all, eU_b, nV_b, nU_b, l,
                                          nodeU, nodeV, nodeUn);
        gemm_edge<<<N_EDGES / 64, 256, 0, stream>>>(edge_bf, BtE, nodeU, src, dst,
                                                    gate_bf, gsum, gsumsq, nsum);
        node_msg<<<N_NODES, 256, 0, stream>>>(edge_bf, nodeV, nodeUn, src,
                                              csr_offs, csr_eidx, ssum_cur, ssum_nxt, aggv);
        edge_finalize<<<N_EDGES / EF_ROWS, 256, 0, stream>>>(edge, edge_bf, gate_bf,
                                                             gsum, gsumsq,
                                                             bn_e_g + l * H, bn_e_b + l * H,
                                                             ssum_nxt);
        node_stats<<<80, 256, 0, stream>>>(aggv, nsum, nsumsq);
        node_update<<<(NH / 4 + 255) / 256, 256, 0, stream>>>(node, node_bf, aggv,
                                                              nsum, nsumsq,
                                                              bn_n_g + l * H, bn_n_b + l * H,
                                                              gsum);
    }

    classify_loss<<<500, 256, 0, stream>>>(edge, cls_W, cls_b, src, dst, y, out);
}

// Round 4
// 3658.980 us; speedup vs baseline: 4.7115x; 1.3527x over previous
//
#include <hip/hip_runtime.h>
#include <hip/hip_bf16.h>
#include <math.h>

#define N_NODES 2000
#define N_EDGES 32000
#define H 300
#define CH 75             // H/4 float4 chunks per row
#define HP 320            // padded H for MFMA K/N
#define NLAYERS 30
#define NH (N_NODES * H)     // 600000
#define EH (N_EDGES * H)     // 9600000
#define NODE_ROWS_PAD 2048
#define WMAT (HP * HP)
#define NREP 32              // stat replicas
#define RSTRIDE 608          // replica row stride (sum | sumsq at +304)
#define SSTRIDE 304

typedef short bf16x8 __attribute__((ext_vector_type(8)));
typedef float f32x4 __attribute__((ext_vector_type(4)));
typedef __hip_bfloat16 bf16;

__device__ __forceinline__ float sigm(float x) { return 1.f / (1.f + __expf(-x)); }

// ---------------------------------------------------------------- utilities
__global__ __launch_bounds__(256) void zero_buf(float* __restrict__ p, int n) {
    int i = blockIdx.x * blockDim.x + threadIdx.x;
    if (i < n) p[i] = 0.f;
}

// --------------------------------------------- weights -> bf16, transposed
__global__ __launch_bounds__(256) void convert_weights(const float* __restrict__ eU,
                                                       const float* __restrict__ eW,
                                                       const float* __restrict__ nU,
                                                       const float* __restrict__ nV,
                                                       bf16* __restrict__ Wt) {
    long long idx = (long long)blockIdx.x * 256 + threadIdx.x;
    if (idx >= (long long)120 * WMAT) return;
    int m = (int)(idx / WMAT);
    int rem = (int)(idx % WMAT);
    int n = rem / HP, k = rem % HP;
    int grp = m / NLAYERS, l = m % NLAYERS;
    float v = 0.f;
    if (n < H && k < H) {
        const float* s = (grp == 0) ? eU : (grp == 1) ? eW : (grp == 2) ? nU : nV;
        v = s[(size_t)l * H * H + (size_t)k * H + n];
    }
    Wt[idx] = __float2bfloat16(v);
}

// ------------------------------------------------------------- CSR by dst
__global__ __launch_bounds__(256) void csr_hist(const int* __restrict__ dst,
                                                int* __restrict__ counts) {
    int i = blockIdx.x * 256 + threadIdx.x;
    if (i < N_EDGES) atomicAdd(&counts[dst[i]], 1);
}

__global__ __launch_bounds__(256) void csr_scan(const int* __restrict__ counts,
                                                int* __restrict__ offs,
                                                int* __restrict__ woff) {
    __shared__ int part[256];
    int t = threadIdx.x;
    int base = t * 8;
    int local[8];
    int s = 0;
#pragma unroll
    for (int j = 0; j < 8; ++j) {
        int c = (base + j < N_NODES) ? counts[base + j] : 0;
        local[j] = s;
        s += c;
    }
    part[t] = s;
    __syncthreads();
    for (int off = 1; off < 256; off <<= 1) {
        int v = (t >= off) ? part[t - off] : 0;
        __syncthreads();
        part[t] += v;
        __syncthreads();
    }
    int pre = (t == 0) ? 0 : part[t - 1];
#pragma unroll
    for (int j = 0; j < 8; ++j) {
        int idx = base + j;
        if (idx < N_NODES) { int v = pre + local[j]; offs[idx] = v; woff[idx] = v; }
    }
    if (t == 255) offs[N_NODES] = part[255];
}

__global__ __launch_bounds__(256) void csr_scatter(const int* __restrict__ src,
                                                   const int* __restrict__ dst,
                                                   int* __restrict__ woff,
                                                   int* __restrict__ eidx,
                                                   int* __restrict__ msrc) {
    int i = blockIdx.x * 256 + threadIdx.x;
    if (i < N_EDGES) {
        int p = atomicAdd(&woff[dst[i]], 1);
        eidx[p] = i;
        msrc[p] = src[i];
    }
}

// ---------------------------------------------------------------- embeddings
__global__ __launch_bounds__(256) void node_embed(const float* __restrict__ x,
                                                  const float* __restrict__ W,
                                                  const float* __restrict__ b,
                                                  float* __restrict__ node,
                                                  bf16* __restrict__ node_bf) {
    int i = blockIdx.x * blockDim.x + threadIdx.x;
    if (i >= NH) return;
    int n = i / H, h = i % H;
    float acc = b[h];
#pragma unroll
    for (int k = 0; k < 4; ++k) acc += x[n * 4 + k] * W[k * H + h];
    node[i] = acc;
    node_bf[(size_t)n * HP + h] = __float2bfloat16(acc);
}

#define ROWS_PB_E 32
__global__ __launch_bounds__(256) void edge_embed(const float* __restrict__ ea,
                                                  const float* __restrict__ dW,
                                                  const float* __restrict__ db,
                                                  const float* __restrict__ tW,
                                                  const float* __restrict__ tb,
                                                  float* __restrict__ edge,
                                                  bf16* __restrict__ edge_bf,
                                                  float* __restrict__ RS0) {
    __shared__ float s_s[H];
    for (int h = threadIdx.x; h < H; h += 256) s_s[h] = 0.f;
    __syncthreads();
    int e0 = blockIdx.x * ROWS_PB_E;
    for (int idx = threadIdx.x; idx < ROWS_PB_E * H; idx += 256) {
        int e = e0 + idx / H, h = idx % H;
        float v;
        if (h < H / 2) v = ea[e * 2 + 0] * dW[h] + db[h];
        else           v = ea[e * 2 + 1] * tW[h - H / 2] + tb[h - H / 2];
        edge[(size_t)e * H + h] = v;
        bf16 bv = __float2bfloat16(v);
        edge_bf[(size_t)e * HP + h] = bv;
        atomicAdd(&s_s[h], sigm(__bfloat162float(bv)));
    }
    __syncthreads();
    for (int h = threadIdx.x; h < H; h += 256)
        atomicAdd(&RS0[(blockIdx.x & (NREP - 1)) * SSTRIDE + h], s_s[h]);
}

// --------------------------------- node GEMMs: 1-wave blocks, 32r x 80c tile
__global__ __launch_bounds__(64) void gemm_node(const bf16* __restrict__ node_bf,
                                                const bf16* __restrict__ Wt_all,
                                                const float* __restrict__ eU_b,
                                                const float* __restrict__ nV_b,
                                                const float* __restrict__ nU_b,
                                                int layer,
                                                float* __restrict__ nodeU,
                                                float* __restrict__ nodeV,
                                                float* __restrict__ nodeUn) {
    int which = blockIdx.z;
    const bf16* Bt; const float* bias; float* out;
    if (which == 0)      { Bt = Wt_all + (size_t)(0 + layer) * WMAT;  bias = eU_b + layer * H; out = nodeU; }
    else if (which == 1) { Bt = Wt_all + (size_t)(90 + layer) * WMAT; bias = nV_b + layer * H; out = nodeV; }
    else                 { Bt = Wt_all + (size_t)(60 + layer) * WMAT; bias = nU_b + layer * H; out = nodeUn; }
    int lane = threadIdx.x;
    int row0 = blockIdx.x * 32, c0 = blockIdx.y * 80;
    int rlo = lane & 15, khi = lane >> 4;
    f32x4 acc[2][5];
#pragma unroll
    for (int rt = 0; rt < 2; ++rt)
#pragma unroll
        for (int ct = 0; ct < 5; ++ct) acc[rt][ct] = (f32x4)0.f;
#pragma unroll 2
    for (int ks = 0; ks < 10; ++ks) {
        int kk = ks * 32 + khi * 8;
        bf16x8 a[2], b[5];
#pragma unroll
        for (int rt = 0; rt < 2; ++rt)
            a[rt] = *(const bf16x8*)(node_bf + (size_t)(row0 + rt * 16 + rlo) * HP + kk);
#pragma unroll
        for (int ct = 0; ct < 5; ++ct)
            b[ct] = *(const bf16x8*)(Bt + (size_t)(c0 + ct * 16 + rlo) * HP + kk);
#pragma unroll
        for (int rt = 0; rt < 2; ++rt)
#pragma unroll
            for (int ct = 0; ct < 5; ++ct)
                acc[rt][ct] = __builtin_amdgcn_mfma_f32_16x16x32_bf16(a[rt], b[ct], acc[rt][ct], 0, 0, 0);
    }
    int rhi = lane >> 4;
#pragma unroll
    for (int ct = 0; ct < 5; ++ct) {
        int col = c0 + ct * 16 + rlo;
        if (col >= H) continue;
        float bv = bias[col];
#pragma unroll
        for (int rt = 0; rt < 2; ++rt)
#pragma unroll
            for (int j = 0; j < 4; ++j) {
                int r = row0 + rt * 16 + rhi * 4 + j;
                if (r < N_NODES) out[(size_t)r * H + col] = acc[rt][ct][j] + bv;
            }
    }
}

// ------------- edge gate GEMM: LDS-staged swizzled A, gather, replica stats
__global__ __launch_bounds__(256) void gemm_edge(const bf16* __restrict__ edge_bf,
                                                 const bf16* __restrict__ Bt,
                                                 const float* __restrict__ nodeU,
                                                 const int* __restrict__ src,
                                                 const int* __restrict__ dst,
                                                 bf16* __restrict__ gate_bf,
                                                 float* __restrict__ RE) {
    __shared__ uint4 smem4[2560];              // 40 KB: A tile, then stats
    bf16* smA = (bf16*)smem4;
    int tid = threadIdx.x;
    int lane = tid & 63, wave = tid >> 6;
    int row0 = blockIdx.x * 64, c0 = wave * 80;

    // stage A tile (64 rows x 320 cols bf16) with chunk^=(row&7) swizzle
    const bf16* Ag = edge_bf + (size_t)row0 * HP;
#pragma unroll
    for (int it = 0; it < 10; ++it) {
        int cid = it * 256 + tid;              // 16B chunk id, 0..2559
        int row = cid / 40, ch = cid % 40;
        uint4 v = *(const uint4*)(Ag + (size_t)cid * 8);
        int sw = ch ^ (row & 7);
        *(uint4*)(smA + row * 320 + (sw << 3)) = v;
    }
    __syncthreads();

    int rlo = lane & 15, khi = lane >> 4;
    f32x4 acc[4][5];
#pragma unroll
    for (int rt = 0; rt < 4; ++rt)
#pragma unroll
        for (int ct = 0; ct < 5; ++ct) acc[rt][ct] = (f32x4)0.f;
#pragma unroll 2
    for (int ks = 0; ks < 10; ++ks) {
        int c = ks * 4 + khi;
        int kk = ks * 32 + khi * 8;
        bf16x8 a[4], b[5];
#pragma unroll
        for (int rt = 0; rt < 4; ++rt) {
            int row = rt * 16 + rlo;
            a[rt] = *(const bf16x8*)(smA + row * 320 + ((c ^ (row & 7)) << 3));
        }
#pragma unroll
        for (int ct = 0; ct < 5; ++ct)
            b[ct] = *(const bf16x8*)(Bt + (size_t)(c0 + ct * 16 + rlo) * HP + kk);
#pragma unroll
        for (int rt = 0; rt < 4; ++rt)
#pragma unroll
            for (int ct = 0; ct < 5; ++ct)
                acc[rt][ct] = __builtin_amdgcn_mfma_f32_16x16x32_bf16(a[rt], b[ct], acc[rt][ct], 0, 0, 0);
    }
    __syncthreads();                            // done with smA
    float* s_g = (float*)smem4;                 // 304 sums
    float* s_g2 = s_g + SSTRIDE;                // 304 sumsq
    for (int i = tid; i < 2 * SSTRIDE; i += 256) s_g[i] = 0.f;
    __syncthreads();

    int rhi = lane >> 4;
    float csum[5] = {0.f, 0.f, 0.f, 0.f, 0.f};
    float csq[5]  = {0.f, 0.f, 0.f, 0.f, 0.f};
#pragma unroll
    for (int rt = 0; rt < 4; ++rt)
#pragma unroll
        for (int j = 0; j < 4; ++j) {
            int r = row0 + rt * 16 + rhi * 4 + j;
            int se = src[r], de = dst[r];
#pragma unroll
            for (int ct = 0; ct < 5; ++ct) {
                int col = c0 + ct * 16 + rlo;
                if (col < H) {
                    float g = acc[rt][ct][j] + nodeU[(size_t)se * H + col] + nodeU[(size_t)de * H + col];
                    gate_bf[(size_t)r * H + col] = __float2bfloat16(g);
                    csum[ct] += g;
                    csq[ct] += g * g;
                }
            }
        }
#pragma unroll
    for (int ct = 0; ct < 5; ++ct) {
        int col = c0 + ct * 16 + rlo;
        if (col < H) {
            atomicAdd(&s_g[col], csum[ct]);
            atomicAdd(&s_g2[col], csq[ct]);
        }
    }
    __syncthreads();
    float* re = RE + (size_t)(blockIdx.x & (NREP - 1)) * RSTRIDE;
    for (int h = tid; h < H; h += 256) {
        atomicAdd(&re[h], s_g[h]);
        atomicAdd(&re[SSTRIDE + h], s_g2[h]);
    }
}

// ------------- CSR gather (2 nodes/block): ssum reduce + msg + node stats
__global__ __launch_bounds__(320) void node_msg(const bf16* __restrict__ edge_bf,
                                                const float* __restrict__ nodeV,
                                                const float* __restrict__ nodeUn,
                                                const int* __restrict__ offs,
                                                const int* __restrict__ eidx,
                                                const int* __restrict__ msrc,
                                                const float* __restrict__ RScur,
                                                float* __restrict__ RSother,
                                                float* __restrict__ RN,
                                                float* __restrict__ aggv) {
    int t = threadIdx.x;
    int bx = blockIdx.x;
    if (bx < NREP && t < SSTRIDE) RSother[bx * SSTRIDE + t] = 0.f;  // prep next accum
    if (t >= H) return;
    float ssr = 0.f;
#pragma unroll 8
    for (int r = 0; r < NREP; ++r) ssr += RScur[r * SSTRIDE + t];
    float inv = 1.f / (ssr + 1e-20f);
    float st1 = 0.f, st2 = 0.f;
    int n0 = bx * 2;
#pragma unroll
    for (int k = 0; k < 2; ++k) {
        int n = n0 + k;
        int beg = offs[n], end = offs[n + 1];
        float a = 0.f;
        if (beg < end) {
            int e = eidx[beg], s = msrc[beg];
            for (int i = beg; i < end; ++i) {
                int e_n = (i + 1 < end) ? eidx[i + 1] : 0;
                int s_n = (i + 1 < end) ? msrc[i + 1] : 0;
                a += sigm(__bfloat162float(edge_bf[(size_t)e * HP + t])) * nodeV[(size_t)s * H + t];
                e = e_n; s = s_n;
            }
        }
        float v = nodeUn[(size_t)n * H + t] + a * inv;
        aggv[(size_t)n * H + t] = v;
        st1 += v; st2 += v * v;
    }
    float* rn = RN + (size_t)(bx & (NREP - 1)) * RSTRIDE;
    atomicAdd(&rn[t], st1);
    atomicAdd(&rn[SSTRIDE + t], st2);
}

// -------- finalize: reduce RE -> scale/off (LDS), BN+residual, ssum replicas
#define EF_ROWS 64
__global__ __launch_bounds__(256) void edge_finalize(float* __restrict__ edge,
                                                     bf16* __restrict__ edge_bf,
                                                     const bf16* __restrict__ gate_bf,
                                                     const float* __restrict__ RE,
                                                     const float* __restrict__ gamma,
                                                     const float* __restrict__ beta,
                                                     float* __restrict__ RSnext) {
    __shared__ float sc_s[SSTRIDE], of_s[SSTRIDE], s_s[SSTRIDE];
    int t = threadIdx.x;
    const float invE = 1.f / N_EDGES;
    for (int i = t; i < SSTRIDE; i += 256) {
        s_s[i] = 0.f;
        if (i < H) {
            float gs = 0.f, gq = 0.f;
#pragma unroll 8
            for (int r = 0; r < NREP; ++r) {
                gs += RE[r * RSTRIDE + i];
                gq += RE[r * RSTRIDE + SSTRIDE + i];
            }
            float mean = gs * invE;
            float var = fmaxf(gq * invE - mean * mean, 0.f);
            float rstd = rsqrtf(var + 1e-5f);
            float sc = rstd * gamma[i];
            sc_s[i] = sc;
            of_s[i] = beta[i] - mean * sc;
        }
    }
    __syncthreads();
    int hc = t % 80, rgrp = t / 80;
    bool act = (hc < CH) && (rgrp < 3);
    float ss[4] = {0.f, 0.f, 0.f, 0.f};
    int col0 = hc * 4;
    if (act) {
        float sc[4], of[4];
#pragma unroll
        for (int j = 0; j < 4; ++j) { sc[j] = sc_s[col0 + j]; of[j] = of_s[col0 + j]; }
        int e0 = blockIdx.x * EF_ROWS;
        for (int r = rgrp; r < EF_ROWS; r += 3) {
            int e = e0 + r;
            float4 ev = *(const float4*)(edge + (size_t)e * H + col0);
            const float* evp = (const float*)&ev;
            union { ushort4 u; bf16 b[4]; } gv, ob;
            gv.u = *(const ushort4*)(gate_bf + (size_t)e * H + col0);
            float nv[4];
#pragma unroll
            for (int j = 0; j < 4; ++j) {
                float g = __bfloat162float(gv.b[j]);
                float val = fmaxf(fmaf(g, sc[j], of[j]), 0.f);
                nv[j] = evp[j] + val;
                ob.b[j] = __float2bfloat16(nv[j]);
                ss[j] += sigm(__bfloat162float(ob.b[j]));
            }
            *(float4*)(edge + (size_t)e * H + col0) = make_float4(nv[0], nv[1], nv[2], nv[3]);
            *(ushort4*)(edge_bf + (size_t)e * HP + col0) = ob.u;
        }
#pragma unroll
        for (int j = 0; j < 4; ++j) atomicAdd(&s_s[col0 + j], ss[j]);
    }
    __syncthreads();
    float* rs = RSnext + (size_t)(blockIdx.x & (NREP - 1)) * SSTRIDE;
    for (int i = t; i < H; i += 256) atomicAdd(&rs[i], s_s[i]);
}

// --------- reduce RN -> node scale/off; zero RN and RE for next layer
__global__ __launch_bounds__(64) void reduceN(const float* __restrict__ RNc,
                                              float* __restrict__ RN,
                                              float* __restrict__ RE,
                                              const float* __restrict__ gamma,
                                              const float* __restrict__ beta,
                                              float* __restrict__ nSc,
                                              float* __restrict__ nOf) {
    int c = blockIdx.x * 64 + threadIdx.x;     // 0..319
    const float invN = 1.f / N_NODES;
    if (c < H) {
        float ns = 0.f, nq = 0.f;
#pragma unroll 8
        for (int r = 0; r < NREP; ++r) {
            ns += RNc[r * RSTRIDE + c];
            nq += RNc[r * RSTRIDE + SSTRIDE + c];
        }
        float mean = ns * invN;
        float var = fmaxf(nq * invN - mean * mean, 0.f);
        float rstd = rsqrtf(var + 1e-5f);
        float sc = rstd * gamma[c];
        nSc[c] = sc;
        nOf[c] = beta[c] - mean * sc;
    }
    if (c < SSTRIDE) {
        for (int r = 0; r < NREP; ++r) {
            RN[r * RSTRIDE + c] = 0.f;
            RN[r * RSTRIDE + SSTRIDE + c] = 0.f;
            RE[r * RSTRIDE + c] = 0.f;
            RE[r * RSTRIDE + SSTRIDE + c] = 0.f;
        }
    }
}

// ------------------- node += relu(aggv*sc+of), write bf16
__global__ __launch_bounds__(256) void node_update(float* __restrict__ node,
                                                   bf16* __restrict__ node_bf,
                                                   const float* __restrict__ aggv,
                                                   const float* __restrict__ nSc,
                                                   const float* __restrict__ nOf) {
    int c = blockIdx.x * 256 + threadIdx.x;
    if (c >= NH / 4) return;
    int n = c / CH, hc = c % CH, col0 = hc * 4;
    float4 v4 = ((const float4*)aggv)[c];
    float4 s4 = *(const float4*)(nSc + col0);
    float4 o4 = *(const float4*)(nOf + col0);
    float4 nd = ((const float4*)node)[c];
    const float* v4p = (const float*)&v4; const float* s4p = (const float*)&s4;
    const float* o4p = (const float*)&o4; const float* ndp = (const float*)&nd;
    union { ushort4 u; bf16 b[4]; } ob;
    float out[4];
#pragma unroll
    for (int j = 0; j < 4; ++j) {
        float g = fmaf(v4p[j], s4p[j], o4p[j]);
        out[j] = ndp[j] + fmaxf(g, 0.f);
        ob.b[j] = __float2bfloat16(out[j]);
    }
    ((float4*)node)[c] = make_float4(out[0], out[1], out[2], out[3]);
    *(ushort4*)(node_bf + (size_t)n * HP + col0) = ob.u;
}

// ------------------------------------------------------- classifier + loss
__global__ __launch_bounds__(256) void classify_loss(const float* __restrict__ edge,
                                                     const float* __restrict__ clsW,
                                                     const float* __restrict__ clsb,
                                                     const int* __restrict__ src,
                                                     const int* __restrict__ dst,
                                                     const float* __restrict__ y,
                                                     float* __restrict__ out) {
    __shared__ float wl[4];
    int lane = threadIdx.x & 63;
    int wid = threadIdx.x >> 6;
    int gw = blockIdx.x * 4 + wid;
    float lsum = 0.f;
    for (int e = gw; e < N_EDGES; e += 2000) {
        float acc = 0.f;
        for (int h = lane; h < H; h += 64) acc += edge[(size_t)e * H + h] * clsW[h];
#pragma unroll
        for (int off = 32; off > 0; off >>= 1) acc += __shfl_down(acc, off, 64);
        if (lane == 0) {
            float z = acc + clsb[0];
            float p = 1.f / (1.f + __expf(-z));
            atomicAdd(&out[(size_t)src[e] * N_NODES + dst[e]], p);
            float pc = fminf(fmaxf(p, 1e-7f), 1.f - 1e-7f);
            lsum += -(y[e] * __logf(pc) + (1.f - y[e]) * log1pf(-pc));
        }
    }
    if (lane == 0) wl[wid] = lsum;
    __syncthreads();
    if (threadIdx.x == 0) {
        float t = wl[0] + wl[1] + wl[2] + wl[3];
        atomicAdd(&out[(size_t)N_NODES * N_NODES], t * (1.f / N_EDGES));
    }
}

// ---------------------------------------------------------------- launcher
extern "C" void kernel_launch(void* const* d_in, const int* in_sizes, int n_in,
                              void* d_out, int out_size, void* d_ws, size_t ws_size,
                              hipStream_t stream) {
    const float* x          = (const float*)d_in[0];
    const float* edge_attr  = (const float*)d_in[1];
    const int*   edge_index = (const int*)d_in[2];
    const float* y          = (const float*)d_in[3];
    const float* node_emb_W = (const float*)d_in[4];
    const float* node_emb_b = (const float*)d_in[5];
    const float* edge_d_W   = (const float*)d_in[6];
    const float* edge_d_b   = (const float*)d_in[7];
    const float* edge_t_W   = (const float*)d_in[8];
    const float* edge_t_b   = (const float*)d_in[9];
    const float* eU_W = (const float*)d_in[10];
    const float* eU_b = (const float*)d_in[11];
    const float* eW_W = (const float*)d_in[12];
    const float* nU_W = (const float*)d_in[14];
    const float* nU_b = (const float*)d_in[15];
    const float* nV_W = (const float*)d_in[16];
    const float* nV_b = (const float*)d_in[17];
    const float* bn_e_g = (const float*)d_in[18];
    const float* bn_e_b = (const float*)d_in[19];
    const float* bn_n_g = (const float*)d_in[20];
    const float* bn_n_b = (const float*)d_in[21];
    const float* cls_W = (const float*)d_in[22];
    const float* cls_b = (const float*)d_in[23];

    const int* src = edge_index;
    const int* dst = edge_index + N_EDGES;

    float* ws     = (float*)d_ws;
    float* edge   = ws;                  // EH
    float* node   = edge + EH;           // NH
    float* nodeU  = node + NH;           // NH
    float* nodeV  = nodeU + NH;          // NH
    float* nodeUn = nodeV + NH;          // NH
    float* aggv   = nodeUn + NH;         // NH
    float* RE     = aggv + NH;           // 32*608        <-- zero region start
    float* RN     = RE + NREP * RSTRIDE;     // 32*608
    float* RS     = RN + NREP * RSTRIDE;     // 2 x 32*304
    float* nSc    = RS + 2 * NREP * SSTRIDE; // 304
    float* nOf    = nSc + SSTRIDE;           // 304
    bf16* node_bf = (bf16*)(nOf + SSTRIDE);               // 2048*320
    bf16* edge_bf = node_bf + (size_t)NODE_ROWS_PAD * HP; // 32000*320
    bf16* gate_bf = edge_bf + (size_t)N_EDGES * HP;       // 32000*300 (not zeroed)
    bf16* Wt_all  = gate_bf + (size_t)N_EDGES * H;        // 120*102400
    int* csr_counts = (int*)(Wt_all + (size_t)120 * WMAT); // 2048
    int* csr_offs   = csr_counts + 2048;
    int* csr_woff   = csr_offs + 2048;
    int* csr_eidx   = csr_woff + 2048;                     // 32000
    int* csr_msrc   = csr_eidx + N_EDGES;                  // 32000

    float* out = (float*)d_out;

    // zero: out, [RE | RN | RS | nScOf | node_bf | edge_bf], csr_counts
    int zlen = (2 * NREP * RSTRIDE + 2 * NREP * SSTRIDE + 2 * SSTRIDE)
             + (NODE_ROWS_PAD * HP + N_EDGES * HP) / 2;
    zero_buf<<<(N_NODES * N_NODES + 1 + 255) / 256, 256, 0, stream>>>(out, N_NODES * N_NODES + 1);
    zero_buf<<<(zlen + 255) / 256, 256, 0, stream>>>(RE, zlen);
    zero_buf<<<8, 256, 0, stream>>>((float*)csr_counts, 2048);

    convert_weights<<<(120 * WMAT + 255) / 256, 256, 0, stream>>>(eU_W, eW_W, nU_W, nV_W, Wt_all);
    csr_hist<<<(N_EDGES + 255) / 256, 256, 0, stream>>>(dst, csr_counts);
    csr_scan<<<1, 256, 0, stream>>>(csr_counts, csr_offs, csr_woff);
    csr_scatter<<<(N_EDGES + 255) / 256, 256, 0, stream>>>(src, dst, csr_woff, csr_eidx, csr_msrc);
    node_embed<<<(NH + 255) / 256, 256, 0, stream>>>(x, node_emb_W, node_emb_b, node, node_bf);
    edge_embed<<<N_EDGES / ROWS_PB_E, 256, 0, stream>>>(edge_attr, edge_d_W, edge_d_b,
                                                        edge_t_W, edge_t_b, edge, edge_bf, RS);

    for (int l = 0; l < NLAYERS; ++l) {
        float* RScur = RS + (size_t)(l & 1) * NREP * SSTRIDE;
        float* RSnxt = RS + (size_t)((l + 1) & 1) * NREP * SSTRIDE;
        const bf16* BtE = Wt_all + (size_t)(30 + l) * WMAT;

        gemm_node<<<dim3(63, 4, 3), 64, 0, stream>>>(node_bf, Wt_all, eU_b, nV_b, nU_b, l,
                                                     nodeU, nodeV, nodeUn);
        gemm_edge<<<N_EDGES / 64, 256, 0, stream>>>(edge_bf, BtE, nodeU, src, dst,
                                                    gate_bf, RE);
        node_msg<<<N_NODES / 2, 320, 0, stream>>>(edge_bf, nodeV, nodeUn,
                                                  csr_offs, csr_eidx, csr_msrc,
                                                  RScur, RSnxt, RN, aggv);
        edge_finalize<<<N_EDGES / EF_ROWS, 256, 0, stream>>>(edge, edge_bf, gate_bf, RE,
                                                             bn_e_g + l * H, bn_e_b + l * H,
                                                             RSnxt);
        reduceN<<<5, 64, 0, stream>>>(RN, RN, RE, bn_n_g + l * H, bn_n_b + l * H, nSc, nOf);
        node_update<<<(NH / 4 + 255) / 256, 256, 0, stream>>>(node, node_bf, aggv, nSc, nOf);
    }

    classify_loss<<<500, 256, 0, stream>>>(edge, cls_W, cls_b, src, dst, y, out);
}